// Round 5
// baseline (202.291 us; speedup 1.0000x reference)
//
#include <hip/hip_runtime.h>
#include <cstddef>

#define BSZ   2
#define NN    384
#define DATOM 512
#define DPAIR 128
#define DHID  32

// ---------------------------------------------------------------------------
// Workspace layout (float offsets):
//   bbh  [BSZ*NN][32] bf16 hi    offset 0         (12288 floats)
//   bbl  [BSZ*NN][32] bf16 lo    offset 12288     (12288 floats)
//   Th   [BSZ*NN][128][32] bf16  offset 24576     (1572864 floats)
//   Tl   [BSZ*NN][128][32] bf16  offset 1597440   (1572864 floats)
// Total 3,170,304 floats (12.7 MB).
// ---------------------------------------------------------------------------

#define COMP4(v,i) ((i)==0?(v).x:(i)==1?(v).y:(i)==2?(v).z:(v).w)

typedef __attribute__((ext_vector_type(8))) short bf16x8;
typedef __attribute__((ext_vector_type(4))) float f32x4;

static __device__ __forceinline__ unsigned short f2bf(float x) {
    unsigned int u = __float_as_uint(x);
    u += 0x7fffu + ((u >> 16) & 1u);          // round-to-nearest-even
    return (unsigned short)(u >> 16);
}
static __device__ __forceinline__ float bf2f(unsigned short h) {
    return __uint_as_float(((unsigned int)h) << 16);
}

// Kernel 1 (FUSED ab+T): block = (ig: 8 rows) x (oct: p-16th).
// Phase 1: ab = (m @ W_in^T + b_in) * op_mask for the block's 8 rows.
//   All blocks compute the 'a' half (h<32) -> LDS; only oct==0 blocks compute
//   the 'b' half (h>=32) -> split-bf16 bbh/bbl (wave-uniform branch).
// Phase 2: T[i,p,y] = sum_x a[i,x]*W_out[p,x*32+y] for the oct's 16 p values;
//   split-bf16 epilogue to Th/Tl ([p][y] = [row][k] layout for k_main A-frag).
__global__ __launch_bounds__(256) void k_abT(
    const float* __restrict__ m, const float* __restrict__ op_mask,
    const float* __restrict__ W_in, const float* __restrict__ b_in,
    const float* __restrict__ W_out,
    unsigned short* __restrict__ bbh, unsigned short* __restrict__ bbl,
    unsigned short* __restrict__ Th, unsigned short* __restrict__ Tl)
{
    __shared__ __align__(16) float alds[8 * DHID];
    const int t   = threadIdx.x;
    const int ig  = blockIdx.x >> 3;   // 0..95
    const int oct = blockIdx.x & 7;    // p base = oct*16
    const int r0  = ig * 8;            // flat (b*NN+i) base

    // ---- phase 1: ab for rows r0..r0+7 ----
    const int h = t >> 2;              // 0..63
    const int q = t & 3;               // d-offset q*4, stride 16 floats
    if (h < DHID || oct == 0) {        // wave-uniform (h>=32 <=> waves 2,3)
        const float* wrow  = W_in + (size_t)h * DATOM + q * 4;
        const float* mbase = m + (size_t)r0 * DATOM + q * 4;
        float acc[8];
#pragma unroll
        for (int r = 0; r < 8; ++r) acc[r] = 0.f;
#pragma unroll
        for (int k = 0; k < 32; ++k) {
            const float4 w4 = *(const float4*)(wrow + k * 16);
#pragma unroll
            for (int r = 0; r < 8; ++r) {
                const float4 m4 = *(const float4*)(mbase + (size_t)r * DATOM + k * 16);
                acc[r] += w4.x * m4.x + w4.y * m4.y + w4.z * m4.z + w4.w * m4.w;
            }
        }
#pragma unroll
        for (int r = 0; r < 8; ++r) {
            acc[r] += __shfl_xor(acc[r], 1);
            acc[r] += __shfl_xor(acc[r], 2);
        }
        if (q == 0) {
            const float bi = b_in[h];
#pragma unroll
            for (int r = 0; r < 8; ++r) {
                const int row = r0 + r;
                const float val = (acc[r] + bi) * op_mask[row];
                if (h < DHID) {
                    alds[r * DHID + h] = val;
                } else {
                    const unsigned short hi = f2bf(val);
                    const float lo = val - bf2f(hi);
                    const size_t idx = (size_t)row * DHID + (h - DHID);
                    bbh[idx] = hi;
                    bbl[idx] = f2bf(lo);
                }
            }
        }
    }
    __syncthreads();

    // ---- phase 2: T for the oct's 16 p values ----
    const int y  = t & 31;
    const int pg = t >> 5;             // 0..7

    float acc[2][8];
#pragma unroll
    for (int c = 0; c < 2; ++c)
#pragma unroll
        for (int i = 0; i < 8; ++i) acc[c][i] = 0.f;

#pragma unroll
    for (int xc = 0; xc < 8; ++xc) {
        float4 a4[8];
#pragma unroll
        for (int i = 0; i < 8; ++i)
            a4[i] = *(const float4*)&alds[i * DHID + xc * 4];  // broadcast
#pragma unroll
        for (int xi = 0; xi < 4; ++xi) {
            const int x = xc * 4 + xi;
            float w[2];
#pragma unroll
            for (int c = 0; c < 2; ++c) {
                const int p = oct * 16 + c * 8 + pg;
                w[c] = W_out[(size_t)p * (DHID * DHID) + x * DHID + y];
            }
#pragma unroll
            for (int i = 0; i < 8; ++i) {
                const float av = COMP4(a4[i], xi);
#pragma unroll
                for (int c = 0; c < 2; ++c) acc[c][i] += av * w[c];
            }
        }
    }
#pragma unroll
    for (int c = 0; c < 2; ++c) {
        const int p = oct * 16 + c * 8 + pg;
#pragma unroll
        for (int i = 0; i < 8; ++i) {
            const float v = acc[c][i];
            const unsigned short hi = f2bf(v);
            const float lo = v - bf2f(hi);
            const size_t idx = (((size_t)(r0 + i)) * DPAIR + p) * DHID + y;
            Th[idx] = hi;
            Tl[idx] = f2bf(lo);
        }
    }
}

// Kernel 2 (SWAPPED-OPERAND MFMA): out[b,i,j,p] =
//   (sum_y bb[b,j,y]*T[b,i,p,y] + b_out[p]) * op_norm.
// Computes D[p][j] = T x bb (A = T-frag, B = bb-frag; both [row][k] 16B/lane).
// D layout: row(p_local)=lg*4+r, col(j_local)=lr => each lane's 4 acc values
// are 4 CONSECUTIVE p => native float4 stores. No LDS, no barriers;
// split-bf16 3-term MFMA. (launch_bounds softened vs prev attempt: default
// occupancy, no forced 170-VGPR cap.)
__global__ __launch_bounds__(256) void k_main(
    const unsigned short* __restrict__ Th, const unsigned short* __restrict__ Tl,
    const unsigned short* __restrict__ bbh, const unsigned short* __restrict__ bbl,
    const float* __restrict__ b_out, const float* __restrict__ op_norm,
    float* __restrict__ out)
{
    const int t    = threadIdx.x;
    const int lane = t & 63;
    const int w    = t >> 6;           // wave 0..3
    const int lr   = lane & 15;        // col: j index within tile
    const int lg   = lane >> 4;        // k-group 0..3; D rows lg*4..lg*4+3
    const int y0   = lg * 8;           // k base (8 consecutive y per lane)

    const int blk = blockIdx.x;        // b*NN + i
    const int b   = blk / NN;

    const unsigned short* tbh = Th + (size_t)blk * (DPAIR * DHID);
    const unsigned short* tbl = Tl + (size_t)blk * (DPAIR * DHID);
    const unsigned short* abh = bbh + (size_t)b * NN * DHID;
    const unsigned short* abl = bbl + (size_t)b * NN * DHID;

    // A-operand frags: A[m=p][k=y]; lane holds T[pt*16+lr][y0..y0+7].
    bf16x8 fh[8], fl[8];
#pragma unroll
    for (int pt = 0; pt < 8; ++pt) {
        const size_t o = ((size_t)(pt * 16 + lr)) * DHID + y0;
        fh[pt] = *(const bf16x8*)(tbh + o);
        fl[pt] = *(const bf16x8*)(tbl + o);
    }

    // bias: lane needs b_out[pt*16 + lg*4 .. +3] per p-tile.
    float4 bo4[8];
#pragma unroll
    for (int pt = 0; pt < 8; ++pt)
        bo4[pt] = ((const float4*)b_out)[pt * 4 + lg];
    const float onorm = op_norm[0];

#pragma unroll 2
    for (int jj = 0; jj < 6; ++jj) {
        const int jt = w * 6 + jj;
        // B-operand frag: B[k=y][n=j]; lane holds bb[jt*16+lr][y0..y0+7].
        const size_t ao = ((size_t)(jt * 16 + lr)) * DHID + y0;
        const bf16x8 bh = *(const bf16x8*)(abh + ao);
        const bf16x8 bl = *(const bf16x8*)(abl + ao);

        f32x4 acc[8];
#pragma unroll
        for (int pt = 0; pt < 8; ++pt) {
            f32x4 c = {0.f, 0.f, 0.f, 0.f};
            c = __builtin_amdgcn_mfma_f32_16x16x32_bf16(fh[pt], bh, c, 0, 0, 0);
            c = __builtin_amdgcn_mfma_f32_16x16x32_bf16(fh[pt], bl, c, 0, 0, 0);
            c = __builtin_amdgcn_mfma_f32_16x16x32_bf16(fl[pt], bh, c, 0, 0, 0);
            acc[pt] = c;
        }

        // D: row(p_local)=lg*4+r, col(j_local)=lr => float4 over p.
        float* orow = out + (((size_t)blk * NN) + jt * 16 + lr) * DPAIR + lg * 4;
#pragma unroll
        for (int pt = 0; pt < 8; ++pt) {
            float4 v;
            v.x = (acc[pt][0] + bo4[pt].x) * onorm;
            v.y = (acc[pt][1] + bo4[pt].y) * onorm;
            v.z = (acc[pt][2] + bo4[pt].z) * onorm;
            v.w = (acc[pt][3] + bo4[pt].w) * onorm;
            *(float4*)(orow + pt * 16) = v;
        }
    }
}

extern "C" void kernel_launch(void* const* d_in, const int* in_sizes, int n_in,
                              void* d_out, int out_size, void* d_ws, size_t ws_size,
                              hipStream_t stream)
{
    const float* m       = (const float*)d_in[0];
    const float* op_mask = (const float*)d_in[1];
    const float* op_norm = (const float*)d_in[2];
    const float* W_in    = (const float*)d_in[3];
    const float* b_in    = (const float*)d_in[4];
    const float* W_out   = (const float*)d_in[5];
    const float* b_out   = (const float*)d_in[6];
    float* out = (float*)d_out;

    float* ws = (float*)d_ws;
    unsigned short* bbh = (unsigned short*)ws;                       // 24576 sh
    unsigned short* bbl = (unsigned short*)(ws + 12288);             // 24576 sh
    unsigned short* Th  = (unsigned short*)(ws + 24576);             // 3145728 sh
    unsigned short* Tl  = (unsigned short*)(ws + 24576 + 1572864);   // 3145728 sh

    hipLaunchKernelGGL(k_abT, dim3(BSZ * NN), dim3(256), 0, stream,
                       m, op_mask, W_in, b_in, W_out, bbh, bbl, Th, Tl);
    hipLaunchKernelGGL(k_main, dim3(BSZ * NN), dim3(256), 0, stream,
                       Th, Tl, bbh, bbl, b_out, op_norm, out);
}

// Round 6
// 183.679 us; speedup vs baseline: 1.1013x; 1.1013x over previous
//
#include <hip/hip_runtime.h>
#include <cstddef>

#define BSZ   2
#define NN    384
#define DATOM 512
#define DPAIR 128
#define DHID  32

// ---------------------------------------------------------------------------
// Workspace layout (float offsets):
//   abuf [BSZ*NN][32]  fp32       offset 0         (24576 floats)
//   bbh  [BSZ*NN][32]  bf16 hi    offset 24576     (12288 floats)
//   bbl  [BSZ*NN][32]  bf16 lo    offset 36864     (12288 floats)
//   Th   [BSZ*NN][128][32] bf16   offset 49152     (1572864 floats)
//   Tl   [BSZ*NN][128][32] bf16   offset 1622016   (1572864 floats)
// ---------------------------------------------------------------------------

#define COMP4(v,i) ((i)==0?(v).x:(i)==1?(v).y:(i)==2?(v).z:(v).w)

typedef __attribute__((ext_vector_type(8))) short bf16x8;
typedef __attribute__((ext_vector_type(4))) float f32x4;

static __device__ __forceinline__ unsigned short f2bf(float x) {
    unsigned int u = __float_as_uint(x);
    u += 0x7fffu + ((u >> 16) & 1u);          // round-to-nearest-even
    return (unsigned short)(u >> 16);
}
static __device__ __forceinline__ float bf2f(unsigned short h) {
    return __uint_as_float(((unsigned int)h) << 16);
}

// Kernel A (round-2 verified): ab = (m @ W_in^T + b_in) * op_mask.
// block = ONE row; h = t>>2, q = t&3 split d 4-ways; quad-shfl reduce.
// 'a' half -> abuf fp32; 'b' half -> split-bf16 bbh/bbl [row][y].
__global__ __launch_bounds__(256) void k_ab(
    const float* __restrict__ m, const float* __restrict__ op_mask,
    const float* __restrict__ W_in, const float* __restrict__ b_in,
    float* __restrict__ abuf,
    unsigned short* __restrict__ bbh, unsigned short* __restrict__ bbl)
{
    const int t   = threadIdx.x;
    const int h   = t >> 2;          // 0..63
    const int q   = t & 3;           // d-offset q*4, stride 16 floats
    const int row = blockIdx.x;      // b*NN + n

    const float* wrow = W_in + (size_t)h * DATOM + q * 4;
    const float* mrow = m + (size_t)row * DATOM + q * 4;
    float acc = 0.f;
#pragma unroll
    for (int k = 0; k < 32; ++k) {
        const float4 w  = *(const float4*)(wrow + k * 16);
        const float4 mm = *(const float4*)(mrow + k * 16);
        acc += w.x * mm.x + w.y * mm.y + w.z * mm.z + w.w * mm.w;
    }
    acc += __shfl_xor(acc, 1);
    acc += __shfl_xor(acc, 2);
    if (q == 0) {
        const float val = (acc + b_in[h]) * op_mask[row];
        if (h < DHID) {
            abuf[(size_t)row * DHID + h] = val;
        } else {
            const unsigned short hi = f2bf(val);
            const float lo = val - bf2f(hi);
            const size_t idx = (size_t)row * DHID + (h - DHID);
            bbh[idx] = hi;
            bbl[idx] = f2bf(lo);
        }
    }
}

// Kernel B (round-2 verified): T[i,p,y] = sum_x a[i,x]*W_out[p,x*32+y];
// split-bf16 epilogue to Th/Tl ([p][y] = [row][k] layout for k_main A-frag).
__global__ __launch_bounds__(256) void k_T(
    const float* __restrict__ abuf, const float* __restrict__ W_out,
    unsigned short* __restrict__ Th, unsigned short* __restrict__ Tl)
{
    __shared__ __align__(16) float alds[8 * DHID];
    const int t   = threadIdx.x;
    const int ig  = blockIdx.x >> 3;   // 0..95
    const int oct = blockIdx.x & 7;    // p base = oct*16
    const int r0  = ig * 8;            // flat (b*NN+i) base

    alds[t] = abuf[(size_t)r0 * DHID + t];
    __syncthreads();

    const int y  = t & 31;
    const int pg = t >> 5;             // 0..7

    float acc[2][8];
#pragma unroll
    for (int c = 0; c < 2; ++c)
#pragma unroll
        for (int i = 0; i < 8; ++i) acc[c][i] = 0.f;

#pragma unroll
    for (int xc = 0; xc < 8; ++xc) {
        float4 a4[8];
#pragma unroll
        for (int i = 0; i < 8; ++i)
            a4[i] = *(const float4*)&alds[i * DHID + xc * 4];  // broadcast
#pragma unroll
        for (int xi = 0; xi < 4; ++xi) {
            const int x = xc * 4 + xi;
            float w[2];
#pragma unroll
            for (int c = 0; c < 2; ++c) {
                const int p = oct * 16 + c * 8 + pg;
                w[c] = W_out[(size_t)p * (DHID * DHID) + x * DHID + y];
            }
#pragma unroll
            for (int i = 0; i < 8; ++i) {
                const float av = COMP4(a4[i], xi);
#pragma unroll
                for (int c = 0; c < 2; ++c) acc[c][i] += av * w[c];
            }
        }
    }
#pragma unroll
    for (int c = 0; c < 2; ++c) {
        const int p = oct * 16 + c * 8 + pg;
#pragma unroll
        for (int i = 0; i < 8; ++i) {
            const float v = acc[c][i];
            const unsigned short hi = f2bf(v);
            const float lo = v - bf2f(hi);
            const size_t idx = (((size_t)(r0 + i)) * DPAIR + p) * DHID + y;
            Th[idx] = hi;
            Tl[idx] = f2bf(lo);
        }
    }
}

// Kernel C (round-5 verified, SWAPPED-OPERAND MFMA): out[b,i,j,p] =
//   (sum_y bb[b,j,y]*T[b,i,p,y] + b_out[p]) * op_norm.
// D[p][j] = T x bb; lane's 4 acc values are 4 CONSECUTIVE p => float4 stores
// (1 KB/wave-instr vs 256B scalar: 4x fewer store instrs, ~23us -> ~6us
// issue; kernel becomes write-BW-bound at ~24us). No LDS, no barriers.
__global__ __launch_bounds__(256) void k_main(
    const unsigned short* __restrict__ Th, const unsigned short* __restrict__ Tl,
    const unsigned short* __restrict__ bbh, const unsigned short* __restrict__ bbl,
    const float* __restrict__ b_out, const float* __restrict__ op_norm,
    float* __restrict__ out)
{
    const int t    = threadIdx.x;
    const int lane = t & 63;
    const int w    = t >> 6;           // wave 0..3
    const int lr   = lane & 15;        // col: j index within tile
    const int lg   = lane >> 4;        // k-group 0..3; D rows lg*4..lg*4+3
    const int y0   = lg * 8;           // k base (8 consecutive y per lane)

    const int blk = blockIdx.x;        // b*NN + i
    const int b   = blk / NN;

    const unsigned short* tbh = Th + (size_t)blk * (DPAIR * DHID);
    const unsigned short* tbl = Tl + (size_t)blk * (DPAIR * DHID);
    const unsigned short* abh = bbh + (size_t)b * NN * DHID;
    const unsigned short* abl = bbl + (size_t)b * NN * DHID;

    // A-operand frags: A[m=p][k=y]; lane holds T[pt*16+lr][y0..y0+7].
    bf16x8 fh[8], fl[8];
#pragma unroll
    for (int pt = 0; pt < 8; ++pt) {
        const size_t o = ((size_t)(pt * 16 + lr)) * DHID + y0;
        fh[pt] = *(const bf16x8*)(tbh + o);
        fl[pt] = *(const bf16x8*)(tbl + o);
    }

    // bias: lane needs b_out[pt*16 + lg*4 .. +3] per p-tile.
    float4 bo4[8];
#pragma unroll
    for (int pt = 0; pt < 8; ++pt)
        bo4[pt] = ((const float4*)b_out)[pt * 4 + lg];
    const float onorm = op_norm[0];

#pragma unroll 2
    for (int jj = 0; jj < 6; ++jj) {
        const int jt = w * 6 + jj;
        // B-operand frag: B[k=y][n=j]; lane holds bb[jt*16+lr][y0..y0+7].
        const size_t ao = ((size_t)(jt * 16 + lr)) * DHID + y0;
        const bf16x8 bh = *(const bf16x8*)(abh + ao);
        const bf16x8 bl = *(const bf16x8*)(abl + ao);

        f32x4 acc[8];
#pragma unroll
        for (int pt = 0; pt < 8; ++pt) {
            f32x4 c = {0.f, 0.f, 0.f, 0.f};
            c = __builtin_amdgcn_mfma_f32_16x16x32_bf16(fh[pt], bh, c, 0, 0, 0);
            c = __builtin_amdgcn_mfma_f32_16x16x32_bf16(fh[pt], bl, c, 0, 0, 0);
            c = __builtin_amdgcn_mfma_f32_16x16x32_bf16(fl[pt], bh, c, 0, 0, 0);
            acc[pt] = c;
        }

        // D: row(p_local)=lg*4+r, col(j_local)=lr => float4 over p.
        float* orow = out + (((size_t)blk * NN) + jt * 16 + lr) * DPAIR + lg * 4;
#pragma unroll
        for (int pt = 0; pt < 8; ++pt) {
            float4 v;
            v.x = (acc[pt][0] + bo4[pt].x) * onorm;
            v.y = (acc[pt][1] + bo4[pt].y) * onorm;
            v.z = (acc[pt][2] + bo4[pt].z) * onorm;
            v.w = (acc[pt][3] + bo4[pt].w) * onorm;
            *(float4*)(orow + pt * 16) = v;
        }
    }
}

extern "C" void kernel_launch(void* const* d_in, const int* in_sizes, int n_in,
                              void* d_out, int out_size, void* d_ws, size_t ws_size,
                              hipStream_t stream)
{
    const float* m       = (const float*)d_in[0];
    const float* op_mask = (const float*)d_in[1];
    const float* op_norm = (const float*)d_in[2];
    const float* W_in    = (const float*)d_in[3];
    const float* b_in    = (const float*)d_in[4];
    const float* W_out   = (const float*)d_in[5];
    const float* b_out   = (const float*)d_in[6];
    float* out = (float*)d_out;

    float* ws = (float*)d_ws;
    float*          abuf = ws;                                   // 24576 f
    unsigned short* bbh  = (unsigned short*)(ws + 24576);        // 24576 sh
    unsigned short* bbl  = (unsigned short*)(ws + 36864);        // 24576 sh
    unsigned short* Th   = (unsigned short*)(ws + 49152);        // 3145728 sh
    unsigned short* Tl   = (unsigned short*)(ws + 49152 + 1572864);

    hipLaunchKernelGGL(k_ab,   dim3(BSZ * NN),           dim3(256), 0, stream,
                       m, op_mask, W_in, b_in, abuf, bbh, bbl);
    hipLaunchKernelGGL(k_T,    dim3((BSZ * NN / 8) * 8), dim3(256), 0, stream,
                       abuf, W_out, Th, Tl);
    hipLaunchKernelGGL(k_main, dim3(BSZ * NN),           dim3(256), 0, stream,
                       Th, Tl, bbh, bbl, b_out, op_norm, out);
}